// Round 3
// baseline (1599.643 us; speedup 1.0000x reference)
//
#include <hip/hip_runtime.h>
#include <math.h>

// ---------------------------------------------------------------------------
// ConsisGADGNN fused kernel, round 2: identical to round 1 (int32 edge-index
// fix). Round-1 bench never ran (GPU acquisition timeout) — resubmitting to
// actually measure the pending hypothesis.
//
// Math: for each edge type t, edge e:
//   x = [feat[src] | feat[dst]]  (128)
//   h = elu(x @ W1_t + b1_t)     (64)
//   h = LN(h) * ln_g + ln_b
//   p = elu(h @ W2_t + b2_t)     (64)
//   BN over all E edges of type t (training-mode batch stats, biased var)
//   out[n] = sum over edges with dst==n of BN(p)
//   res = out @ Wr + br + feat
//
// BN is affine post-stats:  BN(p) = p*scale_t + shift_t, so
//   out[n] = sum_t scale_t (.) rawacc_t[n] + cnt_t[n] * shift_t
// -> single compute pass scattering RAW p + per-(t,c) sum/sumsq accumulation.
// ---------------------------------------------------------------------------

#define NTYPES 3
#define CH 64
#define TILE 64          // edges per block-tile
#define XSTRIDE 129      // odd stride: conflict-free lane-major reads
#define HSTRIDE 65
#define POFF 4160        // P buffer offset (floats) inside shared buf
#define BUF_FLOATS 8320  // max(64*129, 64*65*2)
#define LN_EPS 1e-5f

// MODE 0: scatter raw p into per-type acc + cnt, accumulate BN stats (fast path)
// MODE 1: BN stats only (fallback pass A)
// MODE 2: recompute, scatter normalized p into single N*64 accumulator (fallback pass B)
template <int MODE>
__global__ __launch_bounds__(256, 4) void pass1_kernel(
    const float* __restrict__ feat,
    const float* __restrict__ W1, const float* __restrict__ b1,
    const float* __restrict__ lng, const float* __restrict__ lnb,
    const float* __restrict__ W2, const float* __restrict__ b2,
    const int* __restrict__ esrc, const int* __restrict__ edst,
    int N, int E,
    float* __restrict__ acc,      // MODE0: [T][N][64], MODE2: [N][64]
    int* __restrict__ cnt,        // MODE0: [T][N]
    float* __restrict__ ssum,     // MODE0/1: [T][64]
    float* __restrict__ ssq,      // MODE0/1: [T][64]
    const float* __restrict__ scale,   // MODE2: [T][64]
    const float* __restrict__ shift)   // MODE2: [T][64]
{
    __shared__ float buf[BUF_FLOATS];   // X [64][129]; later H [64][65] @0, P @POFF
    __shared__ float ps[64][5];
    __shared__ float pq[64][5];
    __shared__ int sidx[128];           // [0..63] src, [64..127] dst

    const int tid  = threadIdx.x;
    const int lane = tid & 63;
    const int wu   = __builtin_amdgcn_readfirstlane(tid >> 6);  // wave id, provably uniform
    const int t    = blockIdx.x % NTYPES;
    const int blocksPerType = gridDim.x / NTYPES;
    const int nTiles = (E + TILE - 1) >> 6;

    const float* W1t = W1 + (size_t)t * 128 * CH;
    const float* W2t = W2 + (size_t)t * CH * CH;
    const size_t ebase = (size_t)t * E;

    float rs = 0.f, rq = 0.f;          // running BN partial sums (channel = lane)
    float scv = 0.f, shv = 0.f;
    if (MODE == 2) { scv = scale[t * CH + lane]; shv = shift[t * CH + lane]; }

    for (int tile = blockIdx.x / NTYPES; tile < nTiles; tile += blocksPerType) {
        const int eb = tile << 6;
        // ---- load indices for this tile ----
        if (tid < 128) {
            int e  = tid & 63;
            int ge = eb + e;
            const int* ep = (tid < 64) ? esrc : edst;
            sidx[tid] = (ge < E) ? ep[ebase + ge] : 0;
        }
        __syncthreads();
        // ---- stage X = [feat[src] | feat[dst]] into LDS, coalesced ----
        #pragma unroll 8
        for (int it = 0; it < 32; ++it) {
            int idx = it * 256 + tid;
            int e = idx >> 7, d = idx & 127;
            int row = (d < 64) ? sidx[e] : sidx[64 + e];
            buf[e * XSTRIDE + d] = feat[(size_t)row * CH + (d & 63)];
        }
        __syncthreads();
        // ---- layer 1: h = elu(x @ W1 + b1), lane=edge, wave owns 16 channels ----
        float h[16];
        {
            const float* bb = b1 + t * CH + wu * 16;
            #pragma unroll
            for (int i = 0; i < 16; ++i) h[i] = bb[i];
        }
        #pragma unroll 4
        for (int d = 0; d < 128; ++d) {
            float xd = buf[lane * XSTRIDE + d];
            const float* wr = W1t + d * CH + wu * 16;   // wave-uniform -> s_load
            #pragma unroll
            for (int i = 0; i < 16; ++i) h[i] = fmaf(xd, wr[i], h[i]);
        }
        #pragma unroll
        for (int i = 0; i < 16; ++i) h[i] = h[i] > 0.f ? h[i] : expm1f(h[i]);
        // ---- LayerNorm across the 4 waves' channel chunks ----
        float s = 0.f, q = 0.f;
        #pragma unroll
        for (int i = 0; i < 16; ++i) { s += h[i]; q += h[i] * h[i]; }
        ps[lane][wu] = s; pq[lane][wu] = q;
        __syncthreads();   // also guarantees all waves finished reading X
        float S = ps[lane][0] + ps[lane][1] + ps[lane][2] + ps[lane][3];
        float Q = pq[lane][0] + pq[lane][1] + pq[lane][2] + pq[lane][3];
        float mean = S * (1.f / 64.f);
        float var  = Q * (1.f / 64.f) - mean * mean;
        float rstd = rsqrtf(var + LN_EPS);
        {
            const float* g  = lng + t * CH + wu * 16;
            const float* bq = lnb + t * CH + wu * 16;
            #pragma unroll
            for (int i = 0; i < 16; ++i) {
                float hn = (h[i] - mean) * rstd * g[i] + bq[i];
                buf[lane * HSTRIDE + wu * 16 + i] = hn;   // H overwrites dead X
            }
        }
        __syncthreads();
        // ---- layer 2: p = elu(h @ W2 + b2) ----
        float pv[16];
        {
            const float* bb = b2 + t * CH + wu * 16;
            #pragma unroll
            for (int i = 0; i < 16; ++i) pv[i] = bb[i];
        }
        #pragma unroll 4
        for (int m = 0; m < CH; ++m) {
            float hm = buf[lane * HSTRIDE + m];
            const float* wr = W2t + m * CH + wu * 16;
            #pragma unroll
            for (int i = 0; i < 16; ++i) pv[i] = fmaf(hm, wr[i], pv[i]);
        }
        #pragma unroll
        for (int i = 0; i < 16; ++i) pv[i] = pv[i] > 0.f ? pv[i] : expm1f(pv[i]);
        #pragma unroll
        for (int i = 0; i < 16; ++i) buf[POFF + lane * HSTRIDE + wu * 16 + i] = pv[i];
        __syncthreads();
        // ---- scatter: wave wu handles its 16 edges, lanes = channels (coalesced) ----
        #pragma unroll
        for (int k = 0; k < 16; ++k) {
            int e = wu * 16 + k;
            if (eb + e < E) {
                float v = buf[POFF + e * HSTRIDE + lane];
                int dn = sidx[64 + e];
                if (MODE == 0) {
                    atomicAdd(&acc[((size_t)t * N + dn) * CH + lane], v);
                    rs += v; rq += v * v;
                    if (lane == 0) atomicAdd(&cnt[t * N + dn], 1);
                } else if (MODE == 1) {
                    rs += v; rq += v * v;
                } else {
                    atomicAdd(&acc[(size_t)dn * CH + lane], fmaf(v, scv, shv));
                }
            }
        }
        __syncthreads();   // protect sidx/buf for next tile
    }
    if (MODE == 0 || MODE == 1) {
        atomicAdd(&ssum[t * CH + lane], rs);
        atomicAdd(&ssq[t * CH + lane], rq);
    }
}

__global__ void bn_stats_kernel(const float* __restrict__ ssum, const float* __restrict__ ssq,
                                const float* __restrict__ bng, const float* __restrict__ bnb,
                                float* __restrict__ scale, float* __restrict__ shift, float invE)
{
    int i = threadIdx.x;
    if (i < NTYPES * CH) {
        float m  = ssum[i] * invE;
        float v  = ssq[i] * invE - m * m;
        float sc = bng[i] * rsqrtf(v + LN_EPS);
        scale[i] = sc;
        shift[i] = bnb[i] - m * sc;
    }
}

// INPLACE==0: read per-type raw acc + cnt, apply scale/shift, then @Wr + br + feat
// INPLACE==1: d_out already holds normalized segment-sum; apply @Wr + br + feat in place
template <int INPLACE>
__global__ __launch_bounds__(256, 4) void combine_kernel(
    const float* __restrict__ acc, const int* __restrict__ cnt,
    const float* __restrict__ scale, const float* __restrict__ shift,
    const float* __restrict__ Wr, const float* __restrict__ br,
    const float* __restrict__ feat, float* __restrict__ out, int N)
{
    __shared__ float rowbuf[4][65];
    const int tid = threadIdx.x, lane = tid & 63, w = tid >> 6;
    float wc[64];
    #pragma unroll
    for (int m = 0; m < 64; ++m) wc[m] = Wr[m * CH + lane];   // column `lane`
    float s0 = 0, s1 = 0, s2 = 0, f0 = 0, f1 = 0, f2 = 0;
    if (!INPLACE) {
        s0 = scale[lane];      s1 = scale[CH + lane];  s2 = scale[2 * CH + lane];
        f0 = shift[lane];      f1 = shift[CH + lane];  f2 = shift[2 * CH + lane];
    }
    const float bv = br[lane];
    const int wid = blockIdx.x * 4 + w;
    const int nw  = gridDim.x * 4;
    for (int n = wid; n < N; n += nw) {
        float o;
        if (!INPLACE) {
            o = s0 * acc[(size_t)n * CH + lane]            + (float)cnt[n]         * f0
              + s1 * acc[((size_t)N + n) * CH + lane]      + (float)cnt[N + n]     * f1
              + s2 * acc[((size_t)2 * N + n) * CH + lane]  + (float)cnt[2 * N + n] * f2;
        } else {
            o = out[(size_t)n * CH + lane];
        }
        rowbuf[w][lane] = o;  // wave-private row; in-wave lockstep, no barrier needed
        float r = bv + feat[(size_t)n * CH + lane];
        #pragma unroll
        for (int m = 0; m < 64; ++m) r = fmaf(rowbuf[w][m], wc[m], r);
        out[(size_t)n * CH + lane] = r;
    }
}

extern "C" void kernel_launch(void* const* d_in, const int* in_sizes, int n_in,
                              void* d_out, int out_size, void* d_ws, size_t ws_size,
                              hipStream_t stream) {
    const float* feat = (const float*)d_in[0];
    const float* W1   = (const float*)d_in[1];
    const float* b1   = (const float*)d_in[2];
    const float* lng  = (const float*)d_in[3];
    const float* lnb  = (const float*)d_in[4];
    const float* W2   = (const float*)d_in[5];
    const float* b2   = (const float*)d_in[6];
    const float* bng  = (const float*)d_in[7];
    const float* bnb  = (const float*)d_in[8];
    const float* Wr   = (const float*)d_in[9];
    const float* br   = (const float*)d_in[10];
    const int* esrc   = (const int*)d_in[11];
    const int* edst   = (const int*)d_in[12];

    const int N = in_sizes[0] / CH;
    const int E = in_sizes[11] / NTYPES;
    float* out = (float*)d_out;

    const size_t accB  = (size_t)NTYPES * N * CH * sizeof(float);
    const size_t cntB  = (size_t)NTYPES * N * sizeof(int);
    const size_t statB = (size_t)NTYPES * CH * sizeof(float);
    const size_t needFast = accB + cntB + 4 * statB;

    const int grid1 = 3072;   // multiple of NTYPES
    const int gridC = 2048;

    if (ws_size >= needFast) {
        char* p = (char*)d_ws;
        float* acc  = (float*)p;  p += accB;
        int*   cnt  = (int*)p;    p += cntB;
        float* ssum = (float*)p;  p += statB;
        float* ssq  = (float*)p;  p += statB;
        float* scl  = (float*)p;  p += statB;
        float* shf  = (float*)p;

        hipMemsetAsync(d_ws, 0, accB + cntB + 2 * statB, stream);
        pass1_kernel<0><<<grid1, 256, 0, stream>>>(feat, W1, b1, lng, lnb, W2, b2,
                                                   esrc, edst, N, E,
                                                   acc, cnt, ssum, ssq, nullptr, nullptr);
        bn_stats_kernel<<<1, 192, 0, stream>>>(ssum, ssq, bng, bnb, scl, shf, 1.0f / (float)E);
        combine_kernel<0><<<gridC, 256, 0, stream>>>(acc, cnt, scl, shf, Wr, br, feat, out, N);
    } else {
        // fallback: tiny ws, two compute passes, accumulate into d_out
        char* p = (char*)d_ws;
        float* ssum = (float*)p;  p += statB;
        float* ssq  = (float*)p;  p += statB;
        float* scl  = (float*)p;  p += statB;
        float* shf  = (float*)p;

        hipMemsetAsync(d_ws, 0, 2 * statB, stream);
        hipMemsetAsync(d_out, 0, (size_t)N * CH * sizeof(float), stream);
        pass1_kernel<1><<<grid1, 256, 0, stream>>>(feat, W1, b1, lng, lnb, W2, b2,
                                                   esrc, edst, N, E,
                                                   nullptr, nullptr, ssum, ssq, nullptr, nullptr);
        bn_stats_kernel<<<1, 192, 0, stream>>>(ssum, ssq, bng, bnb, scl, shf, 1.0f / (float)E);
        pass1_kernel<2><<<grid1, 256, 0, stream>>>(feat, W1, b1, lng, lnb, W2, b2,
                                                   esrc, edst, N, E,
                                                   out, nullptr, nullptr, nullptr, scl, shf);
        combine_kernel<1><<<gridC, 256, 0, stream>>>(out, nullptr, nullptr, nullptr,
                                                     Wr, br, feat, out, N);
    }
}

// Round 4
// 806.702 us; speedup vs baseline: 1.9829x; 1.9829x over previous
//
#include <hip/hip_runtime.h>
#include <hip/hip_bf16.h>
#include <math.h>

// ---------------------------------------------------------------------------
// ConsisGADGNN fused kernel, round 4: bf16 MFMA compute core, barrier-free
// main loop (each wave owns its 16 edges; all LDS rows it touches in the loop
// are wave-private). LN via in-register 16-lane shuffle reduction.
//
//   x = [feat[src] | feat[dst]] (128)  -> staged bf16 in LDS (XOR-swizzled)
//   h = elu(x @ W1_t + b1_t)           -> 16x16x32 MFMA, A=X, B=W1^T (LDS)
//   h = LN(h)*g+b                      -> in-register shuffle reduce
//   p = elu(h @ W2_t + b2_t)           -> MFMA, A=Hn (LDS bounce), B=W2 regs
//   raw p scatter-add into acc[t][n][64] + per-(t,ch) sum/sumsq  (BN affine
//   post-stats: out[n] = sum_t scale_t*rawacc_t[n] + cnt_t[n]*shift_t)
//   combine: + @Wr + br + feat
// ---------------------------------------------------------------------------

#define NTYPES 3
#define CH 64
#define LN_EPS 1e-5f

typedef __attribute__((ext_vector_type(8))) short bf16x8;
typedef __attribute__((ext_vector_type(4))) float f32x4;
typedef __attribute__((ext_vector_type(4))) int i32x4;

// LDS layout (bytes):
//  [0,16K)   W1T bf16 [64 n][128 k], row stride 256B, swz ((n&7)<<4)  (persistent)
//  [16K,32K) X   bf16 [64 e][128 d], row stride 256B, swz ((e&7)<<4)
//            (W2T bf16 [64 n][64 k] staged at 16K..24K pre-loop, then dead)
//  [32K,40K) Hn  bf16 [64 e][64 ch], row stride 128B, swz ((e&7)<<4)
#define W1OFF 0
#define XOFF  16384
#define W2OFF 16384
#define HNOFF 32768
#define LDS_BYTES 40960

__device__ __forceinline__ unsigned short f2bf(float x) {
    __hip_bfloat16 h = __float2bfloat16(x);
    return __builtin_bit_cast(unsigned short, h);
}
__device__ __forceinline__ unsigned pack2(float lo, float hi) {
    return (unsigned)f2bf(lo) | ((unsigned)f2bf(hi) << 16);
}
__device__ __forceinline__ float elu(float x) {
    return x > 0.f ? x : (__expf(x) - 1.0f);
}

// MODE 0: scatter raw p + cnt + BN stats (fast path)
// MODE 1: BN stats only (fallback pass A)
// MODE 2: scatter normalized p into [N][64] (fallback pass B)
template <int MODE>
__global__ __launch_bounds__(256, 2) void pass1_kernel(
    const float* __restrict__ feat,
    const float* __restrict__ W1, const float* __restrict__ b1,
    const float* __restrict__ lng, const float* __restrict__ lnb,
    const float* __restrict__ W2, const float* __restrict__ b2,
    const int* __restrict__ esrc, const int* __restrict__ edst,
    int N, int E,
    float* __restrict__ acc, int* __restrict__ cnt,
    float* __restrict__ ssum, float* __restrict__ ssq,
    const float* __restrict__ scale, const float* __restrict__ shift)
{
    __shared__ __align__(16) unsigned char lds[LDS_BYTES];
#define LDS16(o) (*(unsigned short*)(lds + (o)))
#define LDS32(o) (*(unsigned*)(lds + (o)))
#define LDSV(o)  (*(i32x4*)(lds + (o)))

    const int tid  = threadIdx.x;
    const int lane = tid & 63;
    const int w    = tid >> 6;     // wave 0..3
    const int g    = lane >> 4;    // 16-lane group 0..3
    const int c    = lane & 15;
    const int t    = blockIdx.x % NTYPES;
    const int bpt  = gridDim.x / NTYPES;
    const int nTiles = (E + 63) >> 6;

    const float* W1t = W1 + (size_t)t * 128 * CH;
    const float* W2t = W2 + (size_t)t * CH * CH;
    const size_t ebase = (size_t)t * E;
    const float2* feat2 = (const float2*)feat;

    // ---- stage W1^T and W2^T into LDS as bf16 (once per block) ----
    #pragma unroll 4
    for (int it = 0; it < 32; ++it) {
        int id = it * 256 + tid;            // 8192 = 128k x 64n, coalesced over n
        int k = id >> 6, n = id & 63;
        LDS16(W1OFF + n * 256 + ((k * 2) ^ ((n & 7) << 4))) = f2bf(W1t[id]);
    }
    #pragma unroll 4
    for (int it = 0; it < 16; ++it) {
        int id = it * 256 + tid;            // 4096 = 64k x 64n
        int k = id >> 6, n = id & 63;
        LDS16(W2OFF + n * 128 + ((k * 2) ^ ((n & 7) << 4))) = f2bf(W2t[id]);
    }
    __syncthreads();
    // ---- hoist W2 B-frags to registers: [nb][kb] ----
    bf16x8 w2f[4][2];
    #pragma unroll
    for (int nb = 0; nb < 4; ++nb)
        #pragma unroll
        for (int kb = 0; kb < 2; ++kb) {
            int n = nb * 16 + c;
            w2f[nb][kb] = __builtin_bit_cast(bf16x8,
                LDSV(W2OFF + n * 128 + ((kb * 64 + g * 16) ^ ((n & 7) << 4))));
        }
    __syncthreads();   // W2T region becomes X region

    // per-lane channel params (ch = nb*16 + c)
    float b1v[4], b2v[4], lngv[4], lnbv[4], scv[4], shv[4];
    #pragma unroll
    for (int nb = 0; nb < 4; ++nb) {
        int ch = nb * 16 + c;
        b1v[nb]  = b1[t * CH + ch];
        b2v[nb]  = b2[t * CH + ch];
        lngv[nb] = lng[t * CH + ch];
        lnbv[nb] = lnb[t * CH + ch];
        if (MODE == 2) { scv[nb] = scale[t * CH + ch]; shv[nb] = shift[t * CH + ch]; }
    }
    float rs[4] = {0, 0, 0, 0}, rq[4] = {0, 0, 0, 0};

    // =================== barrier-free main loop ===================
    for (int tile = blockIdx.x / NTYPES; tile < nTiles; tile += bpt) {
        const int e0 = (tile << 6) + w * 16;     // this wave's 16 edges
        // ---- indices: lanes 0..15 src, 16..31 dst ----
        int idxv = 0;
        if (lane < 16)      { int ge = e0 + lane;       idxv = (ge < E) ? esrc[ebase + ge] : 0; }
        else if (lane < 32) { int ge = e0 + (lane & 15); idxv = (ge < E) ? edst[ebase + ge] : 0; }
        // ---- stage X rows (wave-private) ----
        const int xin = (lane & 31) * 4 + (lane >> 5) * 128;   // byte within 256B row
        #pragma unroll
        for (int k = 0; k < 16; ++k) {
            int srck = __shfl(idxv, k);
            int dstk = __shfl(idxv, 16 + k);
            int row  = (lane < 32) ? srck : dstk;
            float2 v = feat2[(size_t)row * 32 + (lane & 31)];
            int e = w * 16 + k;
            LDS32(XOFF + e * 256 + (xin ^ ((e & 7) << 4))) = pack2(v.x, v.y);
        }
        // ---- layer 1: h = X @ W1 + b1 (A rows wave-private) ----
        f32x4 hacc[4];
        #pragma unroll
        for (int nb = 0; nb < 4; ++nb) hacc[nb] = (f32x4){b1v[nb], b1v[nb], b1v[nb], b1v[nb]};
        const int xrow = w * 16 + c;
        #pragma unroll
        for (int kb = 0; kb < 4; ++kb) {
            bf16x8 a = __builtin_bit_cast(bf16x8,
                LDSV(XOFF + xrow * 256 + ((kb * 64 + g * 16) ^ ((xrow & 7) << 4))));
            #pragma unroll
            for (int nb = 0; nb < 4; ++nb) {
                int n = nb * 16 + c;
                bf16x8 b = __builtin_bit_cast(bf16x8,
                    LDSV(W1OFF + n * 256 + ((kb * 64 + g * 16) ^ ((n & 7) << 4))));
                hacc[nb] = __builtin_amdgcn_mfma_f32_16x16x32_bf16(a, b, hacc[nb], 0, 0, 0);
            }
        }
        // ---- ELU + LayerNorm, fully in-register ----
        float sI[4] = {0, 0, 0, 0}, qI[4] = {0, 0, 0, 0};
        #pragma unroll
        for (int nb = 0; nb < 4; ++nb)
            #pragma unroll
            for (int i = 0; i < 4; ++i) {
                float h = elu(hacc[nb][i]);
                hacc[nb][i] = h;
                sI[i] += h; qI[i] += h * h;
            }
        #pragma unroll
        for (int i = 0; i < 4; ++i) {
            float s = sI[i], q = qI[i];
            s += __shfl_xor(s, 1);  q += __shfl_xor(q, 1);
            s += __shfl_xor(s, 2);  q += __shfl_xor(q, 2);
            s += __shfl_xor(s, 4);  q += __shfl_xor(q, 4);
            s += __shfl_xor(s, 8);  q += __shfl_xor(q, 8);
            float mean = s * (1.f / 64.f);
            float var  = q * (1.f / 64.f) - mean * mean;
            sI[i] = mean;
            qI[i] = rsqrtf(var + LN_EPS);
        }
        // ---- normalize, write Hn (wave-private rows) ----
        #pragma unroll
        for (int nb = 0; nb < 4; ++nb)
            #pragma unroll
            for (int i = 0; i < 4; ++i) {
                float hn = (hacc[nb][i] - sI[i]) * qI[i] * lngv[nb] + lnbv[nb];
                int row = w * 16 + g * 4 + i;
                int col = nb * 16 + c;
                LDS16(HNOFF + row * 128 + ((col * 2) ^ ((row & 7) << 4))) = f2bf(hn);
            }
        // ---- layer 2: p = Hn @ W2 + b2 ----
        f32x4 pacc[4];
        #pragma unroll
        for (int nb = 0; nb < 4; ++nb) pacc[nb] = (f32x4){b2v[nb], b2v[nb], b2v[nb], b2v[nb]};
        const int hrow = w * 16 + c;
        #pragma unroll
        for (int kb = 0; kb < 2; ++kb) {
            bf16x8 a = __builtin_bit_cast(bf16x8,
                LDSV(HNOFF + hrow * 128 + ((kb * 64 + g * 16) ^ ((hrow & 7) << 4))));
            #pragma unroll
            for (int nb = 0; nb < 4; ++nb)
                pacc[nb] = __builtin_amdgcn_mfma_f32_16x16x32_bf16(a, w2f[nb][kb], pacc[nb], 0, 0, 0);
        }
        // ---- ELU + scatter + BN stats ----
        #pragma unroll
        for (int i = 0; i < 4; ++i) {
            int r  = g * 4 + i;
            int ge = e0 + r;
            int dn = __shfl(idxv, 16 + r);
            bool ok = (ge < E);
            #pragma unroll
            for (int nb = 0; nb < 4; ++nb) {
                float p = elu(pacc[nb][i]);
                if (ok) {
                    if (MODE == 0) {
                        atomicAdd(&acc[((size_t)t * N + dn) * CH + nb * 16 + c], p);
                        rs[nb] += p; rq[nb] += p * p;
                    } else if (MODE == 1) {
                        rs[nb] += p; rq[nb] += p * p;
                    } else {
                        atomicAdd(&acc[(size_t)dn * CH + nb * 16 + c], fmaf(p, scv[nb], shv[nb]));
                    }
                }
            }
            if (MODE == 0 && c == 0 && ok) atomicAdd(&cnt[t * N + dn], 1);
        }
    }
    if (MODE <= 1) {
        #pragma unroll
        for (int nb = 0; nb < 4; ++nb) {
            float s = rs[nb] + __shfl_xor(rs[nb], 16);
            s += __shfl_xor(s, 32);
            float q = rq[nb] + __shfl_xor(rq[nb], 16);
            q += __shfl_xor(q, 32);
            if (lane < 16) {
                atomicAdd(&ssum[t * CH + nb * 16 + lane], s);
                atomicAdd(&ssq[t * CH + nb * 16 + lane], q);
            }
        }
    }
#undef LDS16
#undef LDS32
#undef LDSV
}

__global__ void bn_stats_kernel(const float* __restrict__ ssum, const float* __restrict__ ssq,
                                const float* __restrict__ bng, const float* __restrict__ bnb,
                                float* __restrict__ scale, float* __restrict__ shift, float invE)
{
    int i = threadIdx.x;
    if (i < NTYPES * CH) {
        float m  = ssum[i] * invE;
        float v  = ssq[i] * invE - m * m;
        float sc = bng[i] * rsqrtf(v + LN_EPS);
        scale[i] = sc;
        shift[i] = bnb[i] - m * sc;
    }
}

template <int INPLACE>
__global__ __launch_bounds__(256, 4) void combine_kernel(
    const float* __restrict__ acc, const int* __restrict__ cnt,
    const float* __restrict__ scale, const float* __restrict__ shift,
    const float* __restrict__ Wr, const float* __restrict__ br,
    const float* __restrict__ feat, float* __restrict__ out, int N)
{
    __shared__ float rowbuf[4][65];
    const int tid = threadIdx.x, lane = tid & 63, w = tid >> 6;
    float wc[64];
    #pragma unroll
    for (int m = 0; m < 64; ++m) wc[m] = Wr[m * CH + lane];   // column `lane`
    float s0 = 0, s1 = 0, s2 = 0, f0 = 0, f1 = 0, f2 = 0;
    if (!INPLACE) {
        s0 = scale[lane];      s1 = scale[CH + lane];  s2 = scale[2 * CH + lane];
        f0 = shift[lane];      f1 = shift[CH + lane];  f2 = shift[2 * CH + lane];
    }
    const float bv = br[lane];
    const int wid = blockIdx.x * 4 + w;
    const int nw  = gridDim.x * 4;
    for (int n = wid; n < N; n += nw) {
        float o;
        if (!INPLACE) {
            o = s0 * acc[(size_t)n * CH + lane]            + (float)cnt[n]         * f0
              + s1 * acc[((size_t)N + n) * CH + lane]      + (float)cnt[N + n]     * f1
              + s2 * acc[((size_t)2 * N + n) * CH + lane]  + (float)cnt[2 * N + n] * f2;
        } else {
            o = out[(size_t)n * CH + lane];
        }
        rowbuf[w][lane] = o;  // wave-private row; in-wave lockstep
        float r = bv + feat[(size_t)n * CH + lane];
        #pragma unroll
        for (int m = 0; m < 64; ++m) r = fmaf(rowbuf[w][m], wc[m], r);
        out[(size_t)n * CH + lane] = r;
    }
}

extern "C" void kernel_launch(void* const* d_in, const int* in_sizes, int n_in,
                              void* d_out, int out_size, void* d_ws, size_t ws_size,
                              hipStream_t stream) {
    const float* feat = (const float*)d_in[0];
    const float* W1   = (const float*)d_in[1];
    const float* b1   = (const float*)d_in[2];
    const float* lng  = (const float*)d_in[3];
    const float* lnb  = (const float*)d_in[4];
    const float* W2   = (const float*)d_in[5];
    const float* b2   = (const float*)d_in[6];
    const float* bng  = (const float*)d_in[7];
    const float* bnb  = (const float*)d_in[8];
    const float* Wr   = (const float*)d_in[9];
    const float* br   = (const float*)d_in[10];
    const int* esrc   = (const int*)d_in[11];
    const int* edst   = (const int*)d_in[12];

    const int N = in_sizes[0] / CH;
    const int E = in_sizes[11] / NTYPES;
    float* out = (float*)d_out;

    const size_t accB  = (size_t)NTYPES * N * CH * sizeof(float);
    const size_t cntB  = (size_t)NTYPES * N * sizeof(int);
    const size_t statB = (size_t)NTYPES * CH * sizeof(float);
    const size_t needFast = accB + cntB + 4 * statB;

    const int grid1 = 3072;   // multiple of NTYPES
    const int gridC = 2048;

    if (ws_size >= needFast) {
        char* p = (char*)d_ws;
        float* acc  = (float*)p;  p += accB;
        int*   cnt  = (int*)p;    p += cntB;
        float* ssum = (float*)p;  p += statB;
        float* ssq  = (float*)p;  p += statB;
        float* scl  = (float*)p;  p += statB;
        float* shf  = (float*)p;

        hipMemsetAsync(d_ws, 0, accB + cntB + 2 * statB, stream);
        pass1_kernel<0><<<grid1, 256, 0, stream>>>(feat, W1, b1, lng, lnb, W2, b2,
                                                   esrc, edst, N, E,
                                                   acc, cnt, ssum, ssq, nullptr, nullptr);
        bn_stats_kernel<<<1, 192, 0, stream>>>(ssum, ssq, bng, bnb, scl, shf, 1.0f / (float)E);
        combine_kernel<0><<<gridC, 256, 0, stream>>>(acc, cnt, scl, shf, Wr, br, feat, out, N);
    } else {
        char* p = (char*)d_ws;
        float* ssum = (float*)p;  p += statB;
        float* ssq  = (float*)p;  p += statB;
        float* scl  = (float*)p;  p += statB;
        float* shf  = (float*)p;

        hipMemsetAsync(d_ws, 0, 2 * statB, stream);
        hipMemsetAsync(d_out, 0, (size_t)N * CH * sizeof(float), stream);
        pass1_kernel<1><<<grid1, 256, 0, stream>>>(feat, W1, b1, lng, lnb, W2, b2,
                                                   esrc, edst, N, E,
                                                   nullptr, nullptr, ssum, ssq, nullptr, nullptr);
        bn_stats_kernel<<<1, 192, 0, stream>>>(ssum, ssq, bng, bnb, scl, shf, 1.0f / (float)E);
        pass1_kernel<2><<<grid1, 256, 0, stream>>>(feat, W1, b1, lng, lnb, W2, b2,
                                                   esrc, edst, N, E,
                                                   out, nullptr, nullptr, nullptr, scl, shf);
        combine_kernel<1><<<gridC, 256, 0, stream>>>(out, nullptr, nullptr, nullptr,
                                                     Wr, br, feat, out, N);
    }
}